// Round 5
// baseline (548.812 us; speedup 1.0000x reference)
//
#include <hip/hip_runtime.h>

#define NN     50000
#define HDIM   128
#define DDIM   256
#define RDIM   6
#define NLAYER 3
#define CAP    128      // max edges per node bucket (mean 32)

typedef short bf16x8 __attribute__((ext_vector_type(8)));
typedef float f32x4  __attribute__((ext_vector_type(4)));

__device__ __forceinline__ unsigned short f2bf(float f) {
    union { float f; unsigned int u; } v; v.f = f;
    unsigned int r = v.u + 0x7FFFu + ((v.u >> 16) & 1u);   // RNE
    return (unsigned short)(r >> 16);
}

// ---- prep: zero cnt + cast fp32 weights -> bf16 (one dispatch) ----
__global__ void prep_k(const float* __restrict__ Wup, const float* __restrict__ Ws,
                       unsigned short* __restrict__ wbup, unsigned short* __restrict__ wbs,
                       int* __restrict__ cnt) {
    int t = blockIdx.x * 256 + threadIdx.x;
    if (t < DDIM * HDIM) wbup[t] = f2bf(Wup[t]);
    if (t < NLAYER * DDIM * DDIM) wbs[t] = f2bf(Ws[t]);
    if (t < NN) cnt[t] = 0;
}

// ---- single-pass bucket scatter ----
__global__ void bucket_k(const int* __restrict__ idx, int* __restrict__ cnt,
                         int* __restrict__ bucket, int E) {
    int t = blockIdx.x * 256 + threadIdx.x;
    if (t < E) {
        int n = idx[t];
        int p = atomicAdd(&cnt[n], 1);
        if (p < CAP) bucket[(long)n * CAP + p] = t;
    }
}

// ---- per-edge accumulate; e is wave-uniform (SGPR via readfirstlane) ----
__device__ __forceinline__ void edge_acc(const float* __restrict__ x, const float* __restrict__ rbf,
                                         int e, int lane, const float* w0, const float* w1,
                                         float& a0, float& a1) {
    const float* rp = rbf + (long)e * RDIM;
    float2 r01 = *reinterpret_cast<const float2*>(rp);
    float2 r23 = *reinterpret_cast<const float2*>(rp + 2);
    float2 r45 = *reinterpret_cast<const float2*>(rp + 4);
    float2 xv  = *(reinterpret_cast<const float2*>(x + (long)e * HDIM) + lane);
    float s0 = w0[0] * r01.x + w0[1] * r01.y + w0[2] * r23.x +
               w0[3] * r23.y + w0[4] * r45.x + w0[5] * r45.y;
    float s1 = w1[0] * r01.x + w1[1] * r01.y + w1[2] * r23.x +
               w1[3] * r23.y + w1[4] * r45.x + w1[5] * r45.y;
    a0 += s0 * xv.x; a1 += s1 * xv.y;
}

// ---- LDS A-fragment read (row stride 2*K bytes, XOR-swizzled) ----
template <int K>
__device__ __forceinline__ bf16x8 lds_afrag(const unsigned short* buf, int mi, int kk, int lr, int q) {
    int row = mi * 16 + lr;
    int byte = row * (2 * K) + (((kk * 64 + q * 16)) ^ ((row & 7) << 4));
    return *reinterpret_cast<const bf16x8*>((const char*)buf + byte);
}

// One dense layer on a 64-row LDS tile. FINAL fuses the O=1 output dot.
template <int K, bool SILU, bool FINAL>
__device__ __forceinline__ void layer_compute(
        const unsigned short* Abuf, const unsigned short* __restrict__ W,
        const float* __restrict__ bias, unsigned short* Obuf,
        const float* __restrict__ Wout, float* partialRow, int lane, int w) {
    int lr = lane & 15, q = lane >> 4;
    int cb = w * 64;

    f32x4 acc[4][4];
#pragma unroll
    for (int mi = 0; mi < 4; ++mi)
#pragma unroll
        for (int ni = 0; ni < 4; ++ni) acc[mi][ni] = (f32x4){0.f, 0.f, 0.f, 0.f};

    const unsigned short* bptr[4];
#pragma unroll
    for (int ni = 0; ni < 4; ++ni) bptr[ni] = W + (long)(cb + ni * 16 + lr) * K + q * 8;

#pragma unroll
    for (int kk = 0; kk < K / 32; ++kk) {
        bf16x8 af[4], bfr[4];
#pragma unroll
        for (int mi = 0; mi < 4; ++mi) af[mi] = lds_afrag<K>(Abuf, mi, kk, lr, q);
#pragma unroll
        for (int ni = 0; ni < 4; ++ni) bfr[ni] = *reinterpret_cast<const bf16x8*>(bptr[ni] + kk * 32);
#pragma unroll
        for (int mi = 0; mi < 4; ++mi)
#pragma unroll
            for (int ni = 0; ni < 4; ++ni)
                acc[mi][ni] = __builtin_amdgcn_mfma_f32_16x16x32_bf16(af[mi], bfr[ni], acc[mi][ni], 0, 0, 0);
    }

    float bv[4];
#pragma unroll
    for (int ni = 0; ni < 4; ++ni) bv[ni] = bias[cb + ni * 16 + lr];

    if (!FINAL) {
#pragma unroll
        for (int mi = 0; mi < 4; ++mi)
#pragma unroll
            for (int ni = 0; ni < 4; ++ni) {
                int col = cb + ni * 16 + lr;
#pragma unroll
                for (int jj = 0; jj < 4; ++jj) {
                    int row = mi * 16 + q * 4 + jj;
                    float v = acc[mi][ni][jj] + bv[ni];
                    if (SILU) v = v / (1.f + __expf(-v));
                    int byte = row * 512 + ((2 * col) ^ ((row & 7) << 4));
                    *reinterpret_cast<unsigned short*>((char*)Obuf + byte) = f2bf(v);
                }
            }
    } else {
        float wo[4];
#pragma unroll
        for (int ni = 0; ni < 4; ++ni) wo[ni] = Wout[cb + ni * 16 + lr];
#pragma unroll
        for (int mi = 0; mi < 4; ++mi)
#pragma unroll
            for (int jj = 0; jj < 4; ++jj) {
                float s = 0.f;
#pragma unroll
                for (int ni = 0; ni < 4; ++ni) {
                    float v = acc[mi][ni][jj] + bv[ni];
                    v = v / (1.f + __expf(-v));     // silu
                    s += v * wo[ni];
                }
                s += __shfl_xor(s, 1, 64);
                s += __shfl_xor(s, 2, 64);
                s += __shfl_xor(s, 4, 64);
                s += __shfl_xor(s, 8, 64);
                if (lr == 0) partialRow[mi * 16 + q * 4 + jj] = s;
            }
    }
}

// ======= fused node kernel: gather 64 nodes -> LDS -> 4-layer MLP -> out =====
__global__ __launch_bounds__(256) void node_k(
        const float* __restrict__ x, const float* __restrict__ rbf,
        const float* __restrict__ Wrbf, const int* __restrict__ cnt,
        const int* __restrict__ bucket,
        const unsigned short* __restrict__ wbup, const float* __restrict__ bup,
        const unsigned short* __restrict__ wbs, const float* __restrict__ bs,
        const float* __restrict__ Wout, float* __restrict__ out, int M) {
    __shared__ unsigned short regA[64 * 256];   // 32 KB
    __shared__ unsigned short regB[64 * 256];   // 32 KB
    __shared__ float partial[4][64];

    int tid = threadIdx.x, lane = tid & 63, w = tid >> 6;
    long rbase = (long)blockIdx.x * 64;

    // per-lane gate weights for columns (2*lane, 2*lane+1)
    float w0[RDIM], w1[RDIM];
#pragma unroll
    for (int r = 0; r < RDIM; ++r) {
        w0[r] = Wrbf[(2 * lane) * RDIM + r];
        w1[r] = Wrbf[(2 * lane + 1) * RDIM + r];
    }

    // ---- gather phase: wave w handles local rows w*16 .. w*16+15 ----
    for (int t = 0; t < 16; ++t) {
        int ln = w * 16 + t;
        long n = rbase + ln;
        float a0 = 0.f, a1 = 0.f;
        if (n < M) {
            int c = cnt[n]; if (c > CAP) c = CAP;
            const int* brow = bucket + n * CAP;
            int j = 0;
            for (; j + 8 <= c; j += 8) {
                int4 eA = *reinterpret_cast<const int4*>(brow + j);
                int4 eB = *reinterpret_cast<const int4*>(brow + j + 4);
                int e0 = __builtin_amdgcn_readfirstlane(eA.x);
                int e1 = __builtin_amdgcn_readfirstlane(eA.y);
                int e2 = __builtin_amdgcn_readfirstlane(eA.z);
                int e3 = __builtin_amdgcn_readfirstlane(eA.w);
                int e4 = __builtin_amdgcn_readfirstlane(eB.x);
                int e5 = __builtin_amdgcn_readfirstlane(eB.y);
                int e6 = __builtin_amdgcn_readfirstlane(eB.z);
                int e7 = __builtin_amdgcn_readfirstlane(eB.w);
                edge_acc(x, rbf, e0, lane, w0, w1, a0, a1);
                edge_acc(x, rbf, e1, lane, w0, w1, a0, a1);
                edge_acc(x, rbf, e2, lane, w0, w1, a0, a1);
                edge_acc(x, rbf, e3, lane, w0, w1, a0, a1);
                edge_acc(x, rbf, e4, lane, w0, w1, a0, a1);
                edge_acc(x, rbf, e5, lane, w0, w1, a0, a1);
                edge_acc(x, rbf, e6, lane, w0, w1, a0, a1);
                edge_acc(x, rbf, e7, lane, w0, w1, a0, a1);
            }
            for (; j < c; ++j) {
                int e = __builtin_amdgcn_readfirstlane(brow[j]);
                edge_acc(x, rbf, e, lane, w0, w1, a0, a1);
            }
        }
        // write the gate sums straight into the swizzled LDS A-tile (K=128 layout)
        unsigned int packed = (unsigned int)f2bf(a0) | ((unsigned int)f2bf(a1) << 16);
        int byte = ln * 256 + ((4 * lane) ^ ((ln & 7) << 4));
        *reinterpret_cast<unsigned int*>((char*)regA + byte) = packed;
    }
    __syncthreads();

    // ---- MLP phase ----
    layer_compute<HDIM, false, false>(regA, wbup, bup, regB, nullptr, nullptr, lane, w);
    __syncthreads();
    layer_compute<DDIM, true,  false>(regB, wbs + 0 * DDIM * DDIM, bs + 0 * DDIM, regA, nullptr, nullptr, lane, w);
    __syncthreads();
    layer_compute<DDIM, true,  false>(regA, wbs + 1 * DDIM * DDIM, bs + 1 * DDIM, regB, nullptr, nullptr, lane, w);
    __syncthreads();
    layer_compute<DDIM, true,  true >(regB, wbs + 2 * DDIM * DDIM, bs + 2 * DDIM, nullptr, Wout, &partial[w][0], lane, w);
    __syncthreads();

    if (tid < 64) {
        long row = rbase + tid;
        if (row < M)
            out[row] = partial[0][tid] + partial[1][tid] + partial[2][tid] + partial[3][tid];
    }
}

extern "C" void kernel_launch(void* const* d_in, const int* in_sizes, int n_in,
                              void* d_out, int out_size, void* d_ws, size_t ws_size,
                              hipStream_t stream) {
    const float* x    = (const float*)d_in[0];
    const float* rbf  = (const float*)d_in[1];
    const int*   idx  = (const int*)d_in[2];
    const float* Wrbf = (const float*)d_in[3];
    const float* Wup  = (const float*)d_in[4];
    const float* bup  = (const float*)d_in[5];
    const float* Ws   = (const float*)d_in[6];
    const float* bs   = (const float*)d_in[7];
    const float* Wout = (const float*)d_in[8];
    const int E = in_sizes[2];
    const int N = NN;
    const int mtiles = (N + 63) / 64;          // 782

    char* ws = (char*)d_ws;
    size_t off = 0;
    auto alloc = [&](size_t bytes) -> void* {
        void* p = ws + off;
        off += (bytes + 255) & ~(size_t)255;
        return p;
    };
    int* cnt    = (int*)alloc((size_t)N * 4);
    int* bucket = (int*)alloc((size_t)N * CAP * 4);
    unsigned short* wbup = (unsigned short*)alloc((size_t)DDIM * HDIM * 2);
    unsigned short* wbs  = (unsigned short*)alloc((size_t)NLAYER * DDIM * DDIM * 2);
    (void)ws_size; (void)n_in; (void)out_size;

    prep_k<<<(NLAYER * DDIM * DDIM + 255) / 256, 256, 0, stream>>>(Wup, Ws, wbup, wbs, cnt);
    bucket_k<<<(E + 255) / 256, 256, 0, stream>>>(idx, cnt, bucket, E);
    node_k<<<mtiles, 256, 0, stream>>>(x, rbf, Wrbf, cnt, bucket,
                                       wbup, bup, wbs, bs, Wout, (float*)d_out, N);
}

// Round 9
// 393.674 us; speedup vs baseline: 1.3941x; 1.3941x over previous
//
#include <hip/hip_runtime.h>

#define NN     50000
#define HDIM   128
#define DDIM   256
#define RDIM   6
#define NLAYER 3
#define CAP    128      // max edges per node bucket (mean 32)

typedef short bf16x8 __attribute__((ext_vector_type(8)));
typedef float f32x4  __attribute__((ext_vector_type(4)));

__device__ __forceinline__ unsigned short f2bf(float f) {
    union { float f; unsigned int u; } v; v.f = f;
    unsigned int r = v.u + 0x7FFFu + ((v.u >> 16) & 1u);   // RNE
    return (unsigned short)(r >> 16);
}

// ---- prep: zero cnt + cast fp32 weights -> bf16 (one dispatch) ----
__global__ void prep_k(const float* __restrict__ Wup, const float* __restrict__ Ws,
                       unsigned short* __restrict__ wbup, unsigned short* __restrict__ wbs,
                       int* __restrict__ cnt) {
    int t = blockIdx.x * 256 + threadIdx.x;
    if (t < DDIM * HDIM) wbup[t] = f2bf(Wup[t]);
    if (t < NLAYER * DDIM * DDIM) wbs[t] = f2bf(Ws[t]);
    if (t < NN) cnt[t] = 0;
}

// ---- single-pass bucket scatter ----
__global__ void bucket_k(const int* __restrict__ idx, int* __restrict__ cnt,
                         int* __restrict__ bucket, int E) {
    int t = blockIdx.x * 256 + threadIdx.x;
    if (t < E) {
        int n = idx[t];
        int p = atomicAdd(&cnt[n], 1);
        if (p < CAP) bucket[(long)n * CAP + p] = t;
    }
}

// ---- per-edge accumulate; e is wave-uniform (SGPR via readfirstlane) ----
__device__ __forceinline__ void edge_acc(const float* __restrict__ x, const float* __restrict__ rbf,
                                         int e, int lane, const float* w0, const float* w1,
                                         float& a0, float& a1) {
    const float* rp = rbf + (long)e * RDIM;
    float2 r01 = *reinterpret_cast<const float2*>(rp);
    float2 r23 = *reinterpret_cast<const float2*>(rp + 2);
    float2 r45 = *reinterpret_cast<const float2*>(rp + 4);
    float2 xv  = *(reinterpret_cast<const float2*>(x + (long)e * HDIM) + lane);
    float s0 = w0[0] * r01.x + w0[1] * r01.y + w0[2] * r23.x +
               w0[3] * r23.y + w0[4] * r45.x + w0[5] * r45.y;
    float s1 = w1[0] * r01.x + w1[1] * r01.y + w1[2] * r23.x +
               w1[3] * r23.y + w1[4] * r45.x + w1[5] * r45.y;
    a0 += s0 * xv.x; a1 += s1 * xv.y;
}

// ---- fused edge-gate + gather: one wave per node, 8 edges in flight ----
__global__ __launch_bounds__(256) void gather_k(
        const float* __restrict__ x, const float* __restrict__ rbf,
        const float* __restrict__ Wrbf, const int* __restrict__ cnt,
        const int* __restrict__ bucket, unsigned short* __restrict__ h0, int n_nodes) {
    int wid = threadIdx.x >> 6, lane = threadIdx.x & 63;
    int n = blockIdx.x * 4 + wid;
    if (n >= n_nodes) return;

    int hA = 2 * lane;
    float w0[RDIM], w1[RDIM];
#pragma unroll
    for (int r = 0; r < RDIM; ++r) {
        w0[r] = Wrbf[hA * RDIM + r];
        w1[r] = Wrbf[(hA + 1) * RDIM + r];
    }

    int c = cnt[n]; if (c > CAP) c = CAP;
    const int* brow = bucket + (long)n * CAP;
    float a0 = 0.f, a1 = 0.f;
    int j = 0;
    for (; j + 8 <= c; j += 8) {
        int4 eA = *reinterpret_cast<const int4*>(brow + j);
        int4 eB = *reinterpret_cast<const int4*>(brow + j + 4);
        int e0 = __builtin_amdgcn_readfirstlane(eA.x);
        int e1 = __builtin_amdgcn_readfirstlane(eA.y);
        int e2 = __builtin_amdgcn_readfirstlane(eA.z);
        int e3 = __builtin_amdgcn_readfirstlane(eA.w);
        int e4 = __builtin_amdgcn_readfirstlane(eB.x);
        int e5 = __builtin_amdgcn_readfirstlane(eB.y);
        int e6 = __builtin_amdgcn_readfirstlane(eB.z);
        int e7 = __builtin_amdgcn_readfirstlane(eB.w);
        edge_acc(x, rbf, e0, lane, w0, w1, a0, a1);
        edge_acc(x, rbf, e1, lane, w0, w1, a0, a1);
        edge_acc(x, rbf, e2, lane, w0, w1, a0, a1);
        edge_acc(x, rbf, e3, lane, w0, w1, a0, a1);
        edge_acc(x, rbf, e4, lane, w0, w1, a0, a1);
        edge_acc(x, rbf, e5, lane, w0, w1, a0, a1);
        edge_acc(x, rbf, e6, lane, w0, w1, a0, a1);
        edge_acc(x, rbf, e7, lane, w0, w1, a0, a1);
    }
    for (; j < c; ++j) {
        int e = __builtin_amdgcn_readfirstlane(brow[j]);
        edge_acc(x, rbf, e, lane, w0, w1, a0, a1);
    }

    unsigned int packed = (unsigned int)f2bf(a0) | ((unsigned int)f2bf(a1) << 16);
    *reinterpret_cast<unsigned int*>(h0 + (long)n * HDIM + hA) = packed;
}

// ================= fused MLP: up -> 3x silu -> Wout dot, all in LDS =========
template <int K>
__device__ __forceinline__ bf16x8 lds_afrag(const unsigned short* buf, int mi, int kk, int lr, int q) {
    int row = mi * 16 + lr;
    int byte = row * (2 * K) + (((kk * 64 + q * 16)) ^ ((row & 7) << 4));
    return *reinterpret_cast<const bf16x8*>((const char*)buf + byte);
}

template <int K, bool SILU, bool FINAL>
__device__ __forceinline__ void layer_compute(
        const unsigned short* Abuf, const unsigned short* __restrict__ W,
        const float* __restrict__ bias, unsigned short* Obuf,
        const float* __restrict__ Wout, float* partialRow, int lane, int w) {
    int lr = lane & 15, q = lane >> 4;
    int cb = w * 64;

    f32x4 acc[4][4];
#pragma unroll
    for (int mi = 0; mi < 4; ++mi)
#pragma unroll
        for (int ni = 0; ni < 4; ++ni) acc[mi][ni] = (f32x4){0.f, 0.f, 0.f, 0.f};

    const unsigned short* bptr[4];
#pragma unroll
    for (int ni = 0; ni < 4; ++ni) bptr[ni] = W + (long)(cb + ni * 16 + lr) * K + q * 8;

#pragma unroll
    for (int kk = 0; kk < K / 32; ++kk) {
        bf16x8 af[4], bfr[4];
#pragma unroll
        for (int mi = 0; mi < 4; ++mi) af[mi] = lds_afrag<K>(Abuf, mi, kk, lr, q);
#pragma unroll
        for (int ni = 0; ni < 4; ++ni) bfr[ni] = *reinterpret_cast<const bf16x8*>(bptr[ni] + kk * 32);
#pragma unroll
        for (int mi = 0; mi < 4; ++mi)
#pragma unroll
            for (int ni = 0; ni < 4; ++ni)
                acc[mi][ni] = __builtin_amdgcn_mfma_f32_16x16x32_bf16(af[mi], bfr[ni], acc[mi][ni], 0, 0, 0);
    }

    float bv[4];
#pragma unroll
    for (int ni = 0; ni < 4; ++ni) bv[ni] = bias[cb + ni * 16 + lr];

    if (!FINAL) {
#pragma unroll
        for (int mi = 0; mi < 4; ++mi)
#pragma unroll
            for (int ni = 0; ni < 4; ++ni) {
                int col = cb + ni * 16 + lr;
#pragma unroll
                for (int jj = 0; jj < 4; ++jj) {
                    int row = mi * 16 + q * 4 + jj;
                    float v = acc[mi][ni][jj] + bv[ni];
                    if (SILU) v = v / (1.f + __expf(-v));
                    int byte = row * 512 + ((2 * col) ^ ((row & 7) << 4));
                    *reinterpret_cast<unsigned short*>((char*)Obuf + byte) = f2bf(v);
                }
            }
    } else {
        float wo[4];
#pragma unroll
        for (int ni = 0; ni < 4; ++ni) wo[ni] = Wout[cb + ni * 16 + lr];
#pragma unroll
        for (int mi = 0; mi < 4; ++mi)
#pragma unroll
            for (int jj = 0; jj < 4; ++jj) {
                float s = 0.f;
#pragma unroll
                for (int ni = 0; ni < 4; ++ni) {
                    float v = acc[mi][ni][jj] + bv[ni];
                    v = v / (1.f + __expf(-v));     // silu
                    s += v * wo[ni];
                }
                s += __shfl_xor(s, 1, 64);
                s += __shfl_xor(s, 2, 64);
                s += __shfl_xor(s, 4, 64);
                s += __shfl_xor(s, 8, 64);
                if (lr == 0) partialRow[mi * 16 + q * 4 + jj] = s;
            }
    }
}

__global__ __launch_bounds__(256) void mlp_fused_k(
        const unsigned short* __restrict__ h0,
        const unsigned short* __restrict__ wbup, const float* __restrict__ bup,
        const unsigned short* __restrict__ wbs, const float* __restrict__ bs,
        const float* __restrict__ Wout, float* __restrict__ out, int M) {
    __shared__ unsigned short regA[64 * 256];   // 32 KB
    __shared__ unsigned short regB[64 * 256];   // 32 KB
    __shared__ float partial[4][64];

    int tid = threadIdx.x, lane = tid & 63, w = tid >> 6;
    long rbase = (long)blockIdx.x * 64;

    // stage h0 block (64 x 128 bf16, swizzled, 256 B/row) into regA
#pragma unroll
    for (int s = 0; s < 4; ++s) {
        int idx = s * 256 + tid;            // 0..1023
        int row = idx >> 4, ch = idx & 15;
        bf16x8 v = *reinterpret_cast<const bf16x8*>(h0 + (rbase + row) * HDIM + ch * 8);
        int byte = row * 256 + ((ch * 16) ^ ((row & 7) << 4));
        *reinterpret_cast<bf16x8*>((char*)regA + byte) = v;
    }
    __syncthreads();

    layer_compute<HDIM, false, false>(regA, wbup, bup, regB, nullptr, nullptr, lane, w);
    __syncthreads();
    layer_compute<DDIM, true,  false>(regB, wbs + 0 * DDIM * DDIM, bs + 0 * DDIM, regA, nullptr, nullptr, lane, w);
    __syncthreads();
    layer_compute<DDIM, true,  false>(regA, wbs + 1 * DDIM * DDIM, bs + 1 * DDIM, regB, nullptr, nullptr, lane, w);
    __syncthreads();
    layer_compute<DDIM, true,  true >(regB, wbs + 2 * DDIM * DDIM, bs + 2 * DDIM, nullptr, Wout, &partial[w][0], lane, w);
    __syncthreads();

    if (tid < 64) {
        long row = rbase + tid;
        if (row < M)
            out[row] = partial[0][tid] + partial[1][tid] + partial[2][tid] + partial[3][tid];
    }
}

extern "C" void kernel_launch(void* const* d_in, const int* in_sizes, int n_in,
                              void* d_out, int out_size, void* d_ws, size_t ws_size,
                              hipStream_t stream) {
    const float* x    = (const float*)d_in[0];
    const float* rbf  = (const float*)d_in[1];
    const int*   idx  = (const int*)d_in[2];
    const float* Wrbf = (const float*)d_in[3];
    const float* Wup  = (const float*)d_in[4];
    const float* bup  = (const float*)d_in[5];
    const float* Ws   = (const float*)d_in[6];
    const float* bs   = (const float*)d_in[7];
    const float* Wout = (const float*)d_in[8];
    const int E = in_sizes[2];
    const int N = NN;
    const int mtiles = (N + 63) / 64;          // 782
    const int MPAD = mtiles * 64;              // 50048

    char* ws = (char*)d_ws;
    size_t off = 0;
    auto alloc = [&](size_t bytes) -> void* {
        void* p = ws + off;
        off += (bytes + 255) & ~(size_t)255;
        return p;
    };
    int* cnt    = (int*)alloc((size_t)N * 4);
    int* bucket = (int*)alloc((size_t)N * CAP * 4);
    unsigned short* h0   = (unsigned short*)alloc((size_t)MPAD * HDIM * 2);
    unsigned short* wbup = (unsigned short*)alloc((size_t)DDIM * HDIM * 2);
    unsigned short* wbs  = (unsigned short*)alloc((size_t)NLAYER * DDIM * DDIM * 2);
    (void)ws_size; (void)n_in; (void)out_size;

    prep_k<<<(NLAYER * DDIM * DDIM + 255) / 256, 256, 0, stream>>>(Wup, Ws, wbup, wbs, cnt);
    bucket_k<<<(E + 255) / 256, 256, 0, stream>>>(idx, cnt, bucket, E);
    gather_k<<<(N + 3) / 4, 256, 0, stream>>>(x, rbf, Wrbf, cnt, bucket, h0, N);
    mlp_fused_k<<<mtiles, 256, 0, stream>>>(h0, wbup, bup, wbs, bs, Wout, (float*)d_out, N);
}